// Round 3
// baseline (2445.030 us; speedup 1.0000x reference)
//
#include <hip/hip_runtime.h>
#include <hip/hip_bf16.h>
#include <stdint.h>
#include <stddef.h>

typedef __bf16 bf16;
typedef __bf16 v8bf __attribute__((ext_vector_type(8)));
typedef float  v4f  __attribute__((ext_vector_type(4)));
typedef float  v2f  __attribute__((ext_vector_type(2)));

#define B_ 512
#define T_ 128
#define I_ 512
#define H_ 512
#define C_ 97
#define S_ 26

// ---------------------------------------------------------------- helpers
__device__ __forceinline__ float fast_tanh(float x) {
  float ax = __builtin_fabsf(x);
  float t  = __expf(-2.0f * ax);
  float r  = (1.0f - t) * __builtin_amdgcn_rcpf(1.0f + t);
  return __builtin_copysignf(r, x);
}
__device__ __forceinline__ float fast_sigmoid(float x) {
  float t = __expf(-x);
  return __builtin_amdgcn_rcpf(1.0f + t);
}

// ------------------------------------------------ shared 128x128xK mainloop
// C[M,N] = A[M,K] * Bt[N,K]^T ; LDS tiles [row][32k], register staging.
// ACVT: A source is fp32, converted to bf16 during staging.
template <int KTOT, bool ACVT>
__device__ __forceinline__ void gemm_mainloop(const void* aR0, const void* aR1,
                                              const bf16* bRow0, const bf16* bRow1,
                                              bf16* As, bf16* Bs, int tid,
                                              v4f acc[4][4]) {
  const int wave = tid >> 6, lane = tid & 63;
  const int wr = (wave >> 1) * 64, wc = (wave & 1) * 64;
  const int fr = lane & 15, fq = lane >> 4;
  const int r0 = tid >> 2, k0 = (tid & 3) * 8;
  bf16* a_s0 = As + r0 * 32 + k0;
  bf16* a_s1 = As + (r0 + 64) * 32 + k0;
  bf16* b_s0 = Bs + r0 * 32 + k0;
  bf16* b_s1 = Bs + (r0 + 64) * 32 + k0;
  const bf16* aF[4];
  const bf16* bF[4];
#pragma unroll
  for (int i = 0; i < 4; ++i) {
    aF[i] = As + (wr + i * 16 + fr) * 32 + fq * 8;
    bF[i] = Bs + (wc + i * 16 + fr) * 32 + fq * 8;
  }
  for (int kk = 0; kk < KTOT; kk += 32) {
    v8bf va0, va1;
    if (ACVT) {
      const float* p0 = (const float*)aR0 + kk;
      const float* p1 = (const float*)aR1 + kk;
      v4f f00 = ((const v4f*)p0)[0], f01 = ((const v4f*)p0)[1];
      v4f f10 = ((const v4f*)p1)[0], f11 = ((const v4f*)p1)[1];
#pragma unroll
      for (int j = 0; j < 4; ++j) {
        va0[j] = (bf16)f00[j]; va0[j + 4] = (bf16)f01[j];
        va1[j] = (bf16)f10[j]; va1[j + 4] = (bf16)f11[j];
      }
    } else {
      va0 = *(const v8bf*)((const bf16*)aR0 + kk);
      va1 = *(const v8bf*)((const bf16*)aR1 + kk);
    }
    v8bf vb0 = *(const v8bf*)(bRow0 + kk);
    v8bf vb1 = *(const v8bf*)(bRow1 + kk);
    __syncthreads();  // previous iteration's readers done
    *(v8bf*)a_s0 = va0;
    *(v8bf*)a_s1 = va1;
    *(v8bf*)b_s0 = vb0;
    *(v8bf*)b_s1 = vb1;
    __syncthreads();  // staging visible
    v8bf av[4], bv[4];
#pragma unroll
    for (int i = 0; i < 4; ++i) av[i] = *(const v8bf*)aF[i];
#pragma unroll
    for (int j = 0; j < 4; ++j) bv[j] = *(const v8bf*)bF[j];
#pragma unroll
    for (int i = 0; i < 4; ++i) {
#pragma unroll
      for (int j = 0; j < 4; ++j) {
        acc[i][j] = __builtin_amdgcn_mfma_f32_16x16x32_bf16(av[i], bv[j], acc[i][j], 0, 0, 0);
      }
    }
  }
  __syncthreads();  // safe to reuse LDS after return
}

__device__ __forceinline__ void zero_acc(v4f acc[4][4]) {
  v4f z = {0.f, 0.f, 0.f, 0.f};
#pragma unroll
  for (int i = 0; i < 4; ++i)
#pragma unroll
    for (int j = 0; j < 4; ++j) acc[i][j] = z;
}

// ---------------------------------------------------------------- prep

// generic fp32 -> bf16 convert, 4 elems/thread (n multiple of 1024)
__global__ void k_cvt(const float* __restrict__ src, bf16* __restrict__ dst, int n) {
  int i = (blockIdx.x * 256 + threadIdx.x) * 4;
  if (i + 3 < n) {
    v4f f = *(const v4f*)(src + i);
#pragma unroll
    for (int j = 0; j < 4; ++j) dst[i + j] = (bf16)f[j];
  }
}

// Wcat[2048][1024] = bf16([W_ih(:, :512) | W_hh])
__global__ void k_repack(const float* __restrict__ Wih, const float* __restrict__ Whh,
                         bf16* __restrict__ Wcat) {
  int n = blockIdx.x;
  int t = threadIdx.x;
#pragma unroll
  for (int j = 0; j < 4; ++j) {
    int k = t * 4 + j;  // 0..1023
    float v = (k < 512) ? Wih[(size_t)n * 609 + k] : Whh[(size_t)n * 512 + (k - 512)];
    Wcat[(size_t)n * 1024 + k] = (bf16)v;
  }
}

// Wgen16[128][512]: rows <97 from W_gen, rest zero
__global__ void k_prep_gen(const float* __restrict__ Wg, bf16* __restrict__ Wgen16) {
  int row = blockIdx.x;          // 0..127
  int t = threadIdx.x;           // 0..255
#pragma unroll
  for (int j = 0; j < 2; ++j) {
    int k = t * 2 + j;
    float v = (row < C_) ? Wg[(size_t)row * 512 + k] : 0.0f;
    Wgen16[(size_t)row * 512 + k] = (bf16)v;
  }
}

// ---------------------------------------------------------------- kernels

// F[b,t,h] = batch_H[b,t,:] . W_feat[h,:]  (raw feat)  M=65536 N=512 K=512
__global__ __launch_bounds__(256, 2) void k_feat(const float* __restrict__ A,
                                                 const bf16* __restrict__ Bw,
                                                 bf16* __restrict__ F) {
  __shared__ bf16 As[128 * 32];
  __shared__ bf16 Bs[128 * 32];
  const int tid = threadIdx.x;
  const int m0 = blockIdx.x * 128, n0 = blockIdx.y * 128;
  const int r0 = tid >> 2, k0 = (tid & 3) * 8;
  const float* aRow0 = A + (size_t)(m0 + r0) * 512 + k0;
  const float* aRow1 = A + (size_t)(m0 + r0 + 64) * 512 + k0;
  const bf16* bRow0 = Bw + (size_t)(n0 + r0) * 512 + k0;
  const bf16* bRow1 = Bw + (size_t)(n0 + r0 + 64) * 512 + k0;
  v4f acc[4][4];
  zero_acc(acc);
  gemm_mainloop<512, true>(aRow0, aRow1, bRow0, bRow1, As, Bs, tid, acc);
  const int wave = tid >> 6, lane = tid & 63;
  const int wr = (wave >> 1) * 64, wc = (wave & 1) * 64;
  const int fr = lane & 15, fq = lane >> 4;
#pragma unroll
  for (int i = 0; i < 4; ++i) {
#pragma unroll
    for (int j = 0; j < 4; ++j) {
      int col = n0 + wc + j * 16 + fr;
#pragma unroll
      for (int r = 0; r < 4; ++r) {
        int row = m0 + wr + i * 16 + fq * 4 + r;
        F[(size_t)row * 512 + col] = (bf16)acc[i][j][r];
      }
    }
  }
}

// P[b,h] = h_state[b,:] . W_hid[h,:] + b_hid[h]   (raw hp)  M=N=K=512
__global__ __launch_bounds__(256, 2) void k_hp(const bf16* __restrict__ xb_cur,
                                               const bf16* __restrict__ Whid16,
                                               const float* __restrict__ b_hid,
                                               float* __restrict__ P) {
  __shared__ bf16 As[128 * 32];
  __shared__ bf16 Bs[128 * 32];
  const int tid = threadIdx.x;
  const int m0 = blockIdx.x * 128, n0 = blockIdx.y * 128;
  const int r0 = tid >> 2, k0 = (tid & 3) * 8;
  const bf16* aRow0 = xb_cur + (size_t)(m0 + r0) * 1024 + 512 + k0;
  const bf16* aRow1 = xb_cur + (size_t)(m0 + r0 + 64) * 1024 + 512 + k0;
  const bf16* bRow0 = Whid16 + (size_t)(n0 + r0) * 512 + k0;
  const bf16* bRow1 = Whid16 + (size_t)(n0 + r0 + 64) * 512 + k0;
  v4f acc[4][4];
  zero_acc(acc);
  gemm_mainloop<512, false>(aRow0, aRow1, bRow0, bRow1, As, Bs, tid, acc);
  const int wave = tid >> 6, lane = tid & 63;
  const int wr = (wave >> 1) * 64, wc = (wave & 1) * 64;
  const int fr = lane & 15, fq = lane >> 4;
#pragma unroll
  for (int i = 0; i < 4; ++i) {
#pragma unroll
    for (int j = 0; j < 4; ++j) {
      int col = n0 + wc + j * 16 + fr;
      float bh = b_hid[col];
#pragma unroll
      for (int r = 0; r < 4; ++r) {
        int row = m0 + wr + i * 16 + fq * 4 + r;
        P[(size_t)row * 512 + col] = acc[i][j][r] + bh;
      }
    }
  }
}

// attention: e[b,t] = sum_h w[h]*tanh(F[b,t,h]+P[b,h]); softmax; ctx -> xb_cur[:, :512]
__global__ __launch_bounds__(256) void k_attn(const bf16* __restrict__ F,
                                              const float* __restrict__ P,
                                              const float* __restrict__ w_score,
                                              const float* __restrict__ bH,
                                              bf16* __restrict__ xb_cur) {
  const int b = blockIdx.x;
  const int tid = threadIdx.x, wave = tid >> 6, lane = tid & 63;
  __shared__ float e_s[T_];
  __shared__ float alpha_s[T_];
  float Pv[8], Wv[8];
  {
    const float* p = P + (size_t)b * H_ + lane * 8;
#pragma unroll
    for (int j = 0; j < 8; ++j) Pv[j] = p[j];
    const float* w = w_score + lane * 8;
#pragma unroll
    for (int j = 0; j < 8; ++j) Wv[j] = w[j];
  }
  for (int t = wave; t < T_; t += 4) {
    const v8bf Fv = *(const v8bf*)(F + ((size_t)b * T_ + t) * H_ + lane * 8);
    float acc = 0.f;
#pragma unroll
    for (int j = 0; j < 8; ++j) {
      acc = fmaf(Wv[j], fast_tanh((float)Fv[j] + Pv[j]), acc);
    }
#pragma unroll
    for (int off = 32; off; off >>= 1) acc += __shfl_down(acc, off, 64);
    if (lane == 0) e_s[t] = acc;
  }
  __syncthreads();
  if (wave == 0) {
    float e0 = e_s[lane], e1 = e_s[lane + 64];
    float m = fmaxf(e0, e1);
#pragma unroll
    for (int off = 32; off; off >>= 1) m = fmaxf(m, __shfl_down(m, off, 64));
    m = __shfl(m, 0, 64);
    float x0 = __expf(e0 - m), x1 = __expf(e1 - m);
    float ssum = x0 + x1;
#pragma unroll
    for (int off = 32; off; off >>= 1) ssum += __shfl_down(ssum, off, 64);
    ssum = __shfl(ssum, 0, 64);
    float inv = __builtin_amdgcn_rcpf(ssum);
    alpha_s[lane] = x0 * inv;
    alpha_s[lane + 64] = x1 * inv;
  }
  __syncthreads();
  // ctx[b, i0..i0+1]
  const int i0 = tid * 2;
  float c0 = 0.f, c1 = 0.f;
  const float* bhp = bH + (size_t)b * T_ * I_ + i0;
  for (int t = 0; t < T_; ++t) {
    float a = alpha_s[t];
    v2f p = *(const v2f*)(bhp + (size_t)t * I_);
    c0 = fmaf(a, p[0], c0);
    c1 = fmaf(a, p[1], c1);
  }
  xb_cur[(size_t)b * 1024 + i0]     = (bf16)c0;
  xb_cur[(size_t)b * 1024 + i0 + 1] = (bf16)c1;
}

// gates GEMM (M=512, N=2048 permuted, K=1024) + fused one-hot/bias + LSTM cell
// reads xb_cur, writes new h into xb_nxt (ping-pong: no intra-launch race)
__global__ __launch_bounds__(256, 2) void k_gates(const bf16* __restrict__ xb_cur,
                                                  const bf16* __restrict__ Wcat,
                                                  const float* __restrict__ W_ih,
                                                  const float* __restrict__ b_ih,
                                                  const float* __restrict__ b_hh,
                                                  const int* __restrict__ text,
                                                  float* __restrict__ c_state,
                                                  bf16* __restrict__ out_h,
                                                  bf16* __restrict__ xb_nxt, int s) {
  __shared__ union {
    struct { bf16 A[128 * 32]; bf16 Bv[128 * 32]; } st;
    float Cs[128 * 128];
  } sm;
  const int tid = threadIdx.x;
  const int m0 = blockIdx.x * 128;  // batch tile
  const int j0 = blockIdx.y * 32;   // hidden-j tile; block cols = {i,f,g,o} x 32 j
  const int r0 = tid >> 2, k0 = (tid & 3) * 8;
  const int nn0 = r0, nn1 = r0 + 64;
  const int nw0 = (nn0 >> 5) * 512 + j0 + (nn0 & 31);
  const int nw1 = (nn1 >> 5) * 512 + j0 + (nn1 & 31);
  const bf16* aRow0 = xb_cur + (size_t)(m0 + r0) * 1024 + k0;
  const bf16* aRow1 = xb_cur + (size_t)(m0 + r0 + 64) * 1024 + k0;
  const bf16* bRow0 = Wcat + (size_t)nw0 * 1024 + k0;
  const bf16* bRow1 = Wcat + (size_t)nw1 * 1024 + k0;
  v4f acc[4][4];
  zero_acc(acc);
  gemm_mainloop<1024, false>(aRow0, aRow1, bRow0, bRow1, sm.st.A, sm.st.Bv, tid, acc);
  // write raw gates (+bias +one-hot column) into LDS exchange buffer
  const int wave = tid >> 6, lane = tid & 63;
  const int wr = (wave >> 1) * 64, wc = (wave & 1) * 64;
  const int fr = lane & 15, fq = lane >> 4;
#pragma unroll
  for (int j = 0; j < 4; ++j) {
    int cl = wc + j * 16 + fr;                   // local col 0..127
    int nw = (cl >> 5) * 512 + j0 + (cl & 31);   // global gate row in [0,2048)
    float bias = b_ih[nw] + b_hh[nw];
    const float* ohcol = W_ih + (size_t)nw * 609 + 512;
#pragma unroll
    for (int i = 0; i < 4; ++i) {
#pragma unroll
      for (int r = 0; r < 4; ++r) {
        int rl = wr + i * 16 + fq * 4 + r;
        int tc = text[(size_t)(m0 + rl) * S_ + s];
        sm.Cs[rl * 128 + cl] = acc[i][j][r] + bias + ohcol[tc];
      }
    }
  }
  __syncthreads();
  // LSTM elementwise: 128 rows x 32 j = 4096 items
#pragma unroll
  for (int it = 0; it < 16; ++it) {
    int idx = tid + it * 256;
    int r = idx >> 5, q = idx & 31;
    float ig = sm.Cs[r * 128 + q];
    float fg = sm.Cs[r * 128 + 32 + q];
    float gg = sm.Cs[r * 128 + 64 + q];
    float og = sm.Cs[r * 128 + 96 + q];
    size_t cix = (size_t)(m0 + r) * 512 + j0 + q;
    float c2 = fast_sigmoid(fg) * c_state[cix] + fast_sigmoid(ig) * fast_tanh(gg);
    float h2 = fast_sigmoid(og) * fast_tanh(c2);
    c_state[cix] = c2;
    bf16 hb = (bf16)h2;
    xb_nxt[(size_t)(m0 + r) * 1024 + 512 + j0 + q] = hb;
    out_h[((size_t)(m0 + r) * S_ + s) * 512 + j0 + q] = hb;
  }
}

// probs[bs, c] = out_h[bs,:] . W_gen[c,:] + b_gen[c]   M=13312 N=97(pad128) K=512
__global__ __launch_bounds__(256, 2) void k_gen(const bf16* __restrict__ out_h,
                                                const bf16* __restrict__ Wgen16,
                                                const float* __restrict__ b_gen,
                                                float* __restrict__ out) {
  __shared__ bf16 As[128 * 32];
  __shared__ bf16 Bs[128 * 32];
  const int tid = threadIdx.x;
  const int m0 = blockIdx.x * 128;
  const int r0 = tid >> 2, k0 = (tid & 3) * 8;
  const bf16* aRow0 = out_h + (size_t)(m0 + r0) * 512 + k0;
  const bf16* aRow1 = out_h + (size_t)(m0 + r0 + 64) * 512 + k0;
  const bf16* bRow0 = Wgen16 + (size_t)r0 * 512 + k0;
  const bf16* bRow1 = Wgen16 + (size_t)(r0 + 64) * 512 + k0;
  v4f acc[4][4];
  zero_acc(acc);
  gemm_mainloop<512, false>(aRow0, aRow1, bRow0, bRow1, As, Bs, tid, acc);
  const int wave = tid >> 6, lane = tid & 63;
  const int wr = (wave >> 1) * 64, wc = (wave & 1) * 64;
  const int fr = lane & 15, fq = lane >> 4;
#pragma unroll
  for (int i = 0; i < 4; ++i) {
#pragma unroll
    for (int j = 0; j < 4; ++j) {
      int col = wc + j * 16 + fr;
      if (col < C_) {
        float bg = b_gen[col];
#pragma unroll
        for (int r = 0; r < 4; ++r) {
          int row = m0 + wr + i * 16 + fq * 4 + r;
          out[(size_t)row * C_ + col] = acc[i][j][r] + bg;
        }
      }
    }
  }
}

// ---------------------------------------------------------------- launch
extern "C" void kernel_launch(void* const* d_in, const int* in_sizes, int n_in,
                              void* d_out, int out_size, void* d_ws, size_t ws_size,
                              hipStream_t stream) {
  (void)in_sizes; (void)n_in; (void)out_size; (void)ws_size;
  const float* batch_H = (const float*)d_in[0];
  const int*   text    = (const int*)d_in[1];
  const float* W_feat  = (const float*)d_in[2];
  const float* W_hid   = (const float*)d_in[3];
  const float* b_hid   = (const float*)d_in[4];
  const float* w_score = (const float*)d_in[5];
  const float* W_ih    = (const float*)d_in[6];
  const float* W_hh    = (const float*)d_in[7];
  const float* b_ih    = (const float*)d_in[8];
  const float* b_hh    = (const float*)d_in[9];
  const float* W_gen   = (const float*)d_in[10];
  const float* b_gen   = (const float*)d_in[11];
  float* out = (float*)d_out;

  char* ws = (char*)d_ws;
  // workspace layout (~90.3 MB total)
  bf16*  F       = (bf16*)(ws);                  // 512*128*512*2 = 67108864
  bf16*  out_h   = (bf16*)(ws + 67108864);       // 13312*512*2   = 13631488
  float* P       = (float*)(ws + 80740352);      // 512*512*4     = 1048576
  bf16*  xb0     = (bf16*)(ws + 81788928);       // 512*1024*2    = 1048576
  bf16*  xb1     = (bf16*)(ws + 82837504);       // 512*1024*2    = 1048576
  float* c_state = (float*)(ws + 83886080);      // 512*512*4     = 1048576
  bf16*  Wcat    = (bf16*)(ws + 84934656);       // 2048*1024*2   = 4194304
  bf16*  Wf16    = (bf16*)(ws + 89128960);       // 512*512*2     = 524288
  bf16*  Whid16  = (bf16*)(ws + 89653248);       // 512*512*2     = 524288
  bf16*  Wgen16  = (bf16*)(ws + 90177536);       // 128*512*2     = 131072

  bf16* xb[2] = {xb0, xb1};

  hipMemsetAsync(xb0, 0, (size_t)512 * 1024 * 2, stream);      // h(step0) = 0
  hipMemsetAsync(c_state, 0, (size_t)512 * 512 * 4, stream);   // c(step0) = 0

  k_cvt<<<dim3(256), 256, 0, stream>>>(W_feat, Wf16, 512 * 512);
  k_cvt<<<dim3(256), 256, 0, stream>>>(W_hid, Whid16, 512 * 512);
  k_repack<<<dim3(2048), 256, 0, stream>>>(W_ih, W_hh, Wcat);
  k_prep_gen<<<dim3(128), 256, 0, stream>>>(W_gen, Wgen16);
  k_feat<<<dim3(512, 4), 256, 0, stream>>>(batch_H, Wf16, F);

  for (int s = 0; s < S_; ++s) {
    bf16* cur = xb[s & 1];
    bf16* nxt = xb[(s + 1) & 1];
    k_hp<<<dim3(4, 4), 256, 0, stream>>>(cur, Whid16, b_hid, P);
    k_attn<<<dim3(512), 256, 0, stream>>>(F, P, w_score, batch_H, cur);
    k_gates<<<dim3(4, 16), 256, 0, stream>>>(cur, Wcat, W_ih, b_ih, b_hh, text,
                                             c_state, out_h, nxt, s);
  }
  k_gen<<<dim3(104, 1), 256, 0, stream>>>(out_h, Wgen16, b_gen, out);
}

// Round 4
// 2168.888 us; speedup vs baseline: 1.1273x; 1.1273x over previous
//
#include <hip/hip_runtime.h>
#include <hip/hip_bf16.h>
#include <stdint.h>
#include <stddef.h>

typedef __bf16 bf16;
typedef __bf16 v8bf __attribute__((ext_vector_type(8)));
typedef float  v4f  __attribute__((ext_vector_type(4)));
typedef float  v2f  __attribute__((ext_vector_type(2)));

#define B_ 512
#define T_ 128
#define I_ 512
#define H_ 512
#define C_ 97
#define S_ 26

// ---------------------------------------------------------------- helpers
__device__ __forceinline__ float fast_tanh(float x) {
  float ax = __builtin_fabsf(x);
  float t  = __expf(-2.0f * ax);
  float r  = (1.0f - t) * __builtin_amdgcn_rcpf(1.0f + t);
  return __builtin_copysignf(r, x);
}
__device__ __forceinline__ float fast_sigmoid(float x) {
  float t = __expf(-x);
  return __builtin_amdgcn_rcpf(1.0f + t);
}

// ------------------------------------------------ shared 128x128xK mainloop
template <int KTOT, bool ACVT>
__device__ __forceinline__ void gemm_mainloop(const void* aR0, const void* aR1,
                                              const bf16* bRow0, const bf16* bRow1,
                                              bf16* As, bf16* Bs, int tid,
                                              v4f acc[4][4]) {
  const int wave = tid >> 6, lane = tid & 63;
  const int wr = (wave >> 1) * 64, wc = (wave & 1) * 64;
  const int fr = lane & 15, fq = lane >> 4;
  const int r0 = tid >> 2, k0 = (tid & 3) * 8;
  bf16* a_s0 = As + r0 * 32 + k0;
  bf16* a_s1 = As + (r0 + 64) * 32 + k0;
  bf16* b_s0 = Bs + r0 * 32 + k0;
  bf16* b_s1 = Bs + (r0 + 64) * 32 + k0;
  const bf16* aF[4];
  const bf16* bF[4];
#pragma unroll
  for (int i = 0; i < 4; ++i) {
    aF[i] = As + (wr + i * 16 + fr) * 32 + fq * 8;
    bF[i] = Bs + (wc + i * 16 + fr) * 32 + fq * 8;
  }
  for (int kk = 0; kk < KTOT; kk += 32) {
    v8bf va0, va1;
    if (ACVT) {
      const float* p0 = (const float*)aR0 + kk;
      const float* p1 = (const float*)aR1 + kk;
      v4f f00 = ((const v4f*)p0)[0], f01 = ((const v4f*)p0)[1];
      v4f f10 = ((const v4f*)p1)[0], f11 = ((const v4f*)p1)[1];
#pragma unroll
      for (int j = 0; j < 4; ++j) {
        va0[j] = (bf16)f00[j]; va0[j + 4] = (bf16)f01[j];
        va1[j] = (bf16)f10[j]; va1[j + 4] = (bf16)f11[j];
      }
    } else {
      va0 = *(const v8bf*)((const bf16*)aR0 + kk);
      va1 = *(const v8bf*)((const bf16*)aR1 + kk);
    }
    v8bf vb0 = *(const v8bf*)(bRow0 + kk);
    v8bf vb1 = *(const v8bf*)(bRow1 + kk);
    __syncthreads();
    *(v8bf*)a_s0 = va0;
    *(v8bf*)a_s1 = va1;
    *(v8bf*)b_s0 = vb0;
    *(v8bf*)b_s1 = vb1;
    __syncthreads();
    v8bf av[4], bv[4];
#pragma unroll
    for (int i = 0; i < 4; ++i) av[i] = *(const v8bf*)aF[i];
#pragma unroll
    for (int j = 0; j < 4; ++j) bv[j] = *(const v8bf*)bF[j];
#pragma unroll
    for (int i = 0; i < 4; ++i) {
#pragma unroll
      for (int j = 0; j < 4; ++j) {
        acc[i][j] = __builtin_amdgcn_mfma_f32_16x16x32_bf16(av[i], bv[j], acc[i][j], 0, 0, 0);
      }
    }
  }
  __syncthreads();
}

__device__ __forceinline__ void zero_acc(v4f acc[4][4]) {
  v4f z = {0.f, 0.f, 0.f, 0.f};
#pragma unroll
  for (int i = 0; i < 4; ++i)
#pragma unroll
    for (int j = 0; j < 4; ++j) acc[i][j] = z;
}

// ---------------------------------------------------------------- prep
__global__ void k_cvt(const float* __restrict__ src, bf16* __restrict__ dst, int n) {
  int i = (blockIdx.x * 256 + threadIdx.x) * 4;
  if (i + 3 < n) {
    v4f f = *(const v4f*)(src + i);
#pragma unroll
    for (int j = 0; j < 4; ++j) dst[i + j] = (bf16)f[j];
  }
}

__global__ void k_repack(const float* __restrict__ Wih, const float* __restrict__ Whh,
                         bf16* __restrict__ Wcat) {
  int n = blockIdx.x;
  int t = threadIdx.x;
#pragma unroll
  for (int j = 0; j < 4; ++j) {
    int k = t * 4 + j;
    float v = (k < 512) ? Wih[(size_t)n * 609 + k] : Whh[(size_t)n * 512 + (k - 512)];
    Wcat[(size_t)n * 1024 + k] = (bf16)v;
  }
}

__global__ void k_prep_gen(const float* __restrict__ Wg, bf16* __restrict__ Wgen16) {
  int row = blockIdx.x;
  int t = threadIdx.x;
#pragma unroll
  for (int j = 0; j < 2; ++j) {
    int k = t * 2 + j;
    float v = (row < C_) ? Wg[(size_t)row * 512 + k] : 0.0f;
    Wgen16[(size_t)row * 512 + k] = (bf16)v;
  }
}

// ---------------------------------------------------------------- kernels

// F = batch_H . W_feat^T (raw).  AF32: A source fp32 (fallback) or bf16.
template <bool AF32>
__global__ __launch_bounds__(256, 2) void k_feat(const void* __restrict__ A,
                                                 const bf16* __restrict__ Bw,
                                                 bf16* __restrict__ F) {
  __shared__ bf16 As[128 * 32];
  __shared__ bf16 Bs[128 * 32];
  const int tid = threadIdx.x;
  const int m0 = blockIdx.x * 128, n0 = blockIdx.y * 128;
  const int r0 = tid >> 2, k0 = (tid & 3) * 8;
  const void* aRow0;
  const void* aRow1;
  if (AF32) {
    aRow0 = (const float*)A + (size_t)(m0 + r0) * 512 + k0;
    aRow1 = (const float*)A + (size_t)(m0 + r0 + 64) * 512 + k0;
  } else {
    aRow0 = (const bf16*)A + (size_t)(m0 + r0) * 512 + k0;
    aRow1 = (const bf16*)A + (size_t)(m0 + r0 + 64) * 512 + k0;
  }
  const bf16* bRow0 = Bw + (size_t)(n0 + r0) * 512 + k0;
  const bf16* bRow1 = Bw + (size_t)(n0 + r0 + 64) * 512 + k0;
  v4f acc[4][4];
  zero_acc(acc);
  gemm_mainloop<512, AF32>(aRow0, aRow1, bRow0, bRow1, As, Bs, tid, acc);
  const int wave = tid >> 6, lane = tid & 63;
  const int wr = (wave >> 1) * 64, wc = (wave & 1) * 64;
  const int fr = lane & 15, fq = lane >> 4;
#pragma unroll
  for (int i = 0; i < 4; ++i) {
#pragma unroll
    for (int j = 0; j < 4; ++j) {
      int col = n0 + wc + j * 16 + fr;
#pragma unroll
      for (int r = 0; r < 4; ++r) {
        int row = m0 + wr + i * 16 + fq * 4 + r;
        F[(size_t)row * 512 + col] = (bf16)acc[i][j][r];
      }
    }
  }
}

// P = h . W_hid^T + b_hid (raw).  64x64 tiles, grid 8x8 = 64 blocks.
__global__ __launch_bounds__(256) void k_hp(const bf16* __restrict__ xb_cur,
                                            const bf16* __restrict__ Whid16,
                                            const float* __restrict__ b_hid,
                                            float* __restrict__ P) {
  __shared__ bf16 As[64 * 32];
  __shared__ bf16 Bs[64 * 32];
  const int tid = threadIdx.x, wave = tid >> 6, lane = tid & 63;
  const int m0 = blockIdx.x * 64, n0 = blockIdx.y * 64;
  const int r0 = tid >> 2, k0 = (tid & 3) * 8;
  const bf16* aRow = xb_cur + (size_t)(m0 + r0) * 1024 + 512 + k0;
  const bf16* bRow = Whid16 + (size_t)(n0 + r0) * 512 + k0;
  bf16* a_s = As + r0 * 32 + k0;
  bf16* b_s = Bs + r0 * 32 + k0;
  const int fr = lane & 15, fq = lane >> 4;
  const bf16* aF[4];
#pragma unroll
  for (int i = 0; i < 4; ++i) aF[i] = As + (i * 16 + fr) * 32 + fq * 8;
  const bf16* bF = Bs + (wave * 16 + fr) * 32 + fq * 8;
  v4f acc[4];
  v4f z = {0.f, 0.f, 0.f, 0.f};
#pragma unroll
  for (int i = 0; i < 4; ++i) acc[i] = z;
  for (int kk = 0; kk < 512; kk += 32) {
    v8bf va = *(const v8bf*)(aRow + kk);
    v8bf vb = *(const v8bf*)(bRow + kk);
    __syncthreads();
    *(v8bf*)a_s = va;
    *(v8bf*)b_s = vb;
    __syncthreads();
    v8bf bv = *(const v8bf*)bF;
#pragma unroll
    for (int i = 0; i < 4; ++i) {
      acc[i] = __builtin_amdgcn_mfma_f32_16x16x32_bf16(*(const v8bf*)aF[i], bv, acc[i], 0, 0, 0);
    }
  }
  const int col = n0 + wave * 16 + fr;
  const float bh = b_hid[col];
#pragma unroll
  for (int i = 0; i < 4; ++i) {
#pragma unroll
    for (int r = 0; r < 4; ++r) {
      int row = m0 + i * 16 + fq * 4 + r;
      P[(size_t)row * 512 + col] = acc[i][r] + bh;
    }
  }
}

// attention. CTX16: batch_H stream is bf16 (bH16) or fp32 (fallback).
template <bool CTX16>
__global__ __launch_bounds__(256) void k_attn(const bf16* __restrict__ F,
                                              const float* __restrict__ P,
                                              const float* __restrict__ w_score,
                                              const void* __restrict__ bHv,
                                              bf16* __restrict__ xb_cur) {
  const int b = blockIdx.x;
  const int tid = threadIdx.x, wave = tid >> 6, lane = tid & 63;
  __shared__ float e_s[T_];
  __shared__ float alpha_s[T_];
  __shared__ float red[4][I_];
  float Pv[8], Wv[8];
  {
    const float* p = P + (size_t)b * H_ + lane * 8;
#pragma unroll
    for (int j = 0; j < 8; ++j) Pv[j] = p[j];
    const float* w = w_score + lane * 8;
#pragma unroll
    for (int j = 0; j < 8; ++j) Wv[j] = w[j];
  }
  for (int t = wave; t < T_; t += 4) {
    const v8bf Fv = *(const v8bf*)(F + ((size_t)b * T_ + t) * H_ + lane * 8);
    float acc = 0.f;
#pragma unroll
    for (int j = 0; j < 8; ++j) {
      acc = fmaf(Wv[j], fast_tanh((float)Fv[j] + Pv[j]), acc);
    }
#pragma unroll
    for (int off = 32; off; off >>= 1) acc += __shfl_down(acc, off, 64);
    if (lane == 0) e_s[t] = acc;
  }
  __syncthreads();
  if (wave == 0) {
    float e0 = e_s[lane], e1 = e_s[lane + 64];
    float m = fmaxf(e0, e1);
#pragma unroll
    for (int off = 32; off; off >>= 1) m = fmaxf(m, __shfl_down(m, off, 64));
    m = __shfl(m, 0, 64);
    float x0 = __expf(e0 - m), x1 = __expf(e1 - m);
    float ssum = x0 + x1;
#pragma unroll
    for (int off = 32; off; off >>= 1) ssum += __shfl_down(ssum, off, 64);
    ssum = __shfl(ssum, 0, 64);
    float inv = __builtin_amdgcn_rcpf(ssum);
    alpha_s[lane] = x0 * inv;
    alpha_s[lane + 64] = x1 * inv;
  }
  __syncthreads();
  // ctx: lane owns 8 i's, wave strides t; LDS reduce across waves
  const int i0 = lane * 8;
  float c[8];
#pragma unroll
  for (int j = 0; j < 8; ++j) c[j] = 0.f;
  for (int t = wave; t < T_; t += 4) {
    float a = alpha_s[t];
    if (CTX16) {
      v8bf p = *(const v8bf*)((const bf16*)bHv + ((size_t)b * T_ + t) * I_ + i0);
#pragma unroll
      for (int j = 0; j < 8; ++j) c[j] = fmaf(a, (float)p[j], c[j]);
    } else {
      const float* p = (const float*)bHv + ((size_t)b * T_ + t) * I_ + i0;
      v4f p0 = ((const v4f*)p)[0], p1 = ((const v4f*)p)[1];
#pragma unroll
      for (int j = 0; j < 4; ++j) {
        c[j] = fmaf(a, p0[j], c[j]);
        c[j + 4] = fmaf(a, p1[j], c[j + 4]);
      }
    }
  }
#pragma unroll
  for (int j = 0; j < 8; ++j) red[wave][i0 + j] = c[j];
  __syncthreads();
#pragma unroll
  for (int v = 0; v < 2; ++v) {
    int i = tid * 2 + v;
    float s = red[0][i] + red[1][i] + red[2][i] + red[3][i];
    xb_cur[(size_t)b * 1024 + i] = (bf16)s;
  }
}

// gates GEMM (M=512, N=2048 permuted, K=1024) + fused one-hot/bias + LSTM
__global__ __launch_bounds__(256, 2) void k_gates(const bf16* __restrict__ xb_cur,
                                                  const bf16* __restrict__ Wcat,
                                                  const float* __restrict__ W_ih,
                                                  const float* __restrict__ b_ih,
                                                  const float* __restrict__ b_hh,
                                                  const int* __restrict__ text,
                                                  float* __restrict__ c_state,
                                                  bf16* __restrict__ out_h,
                                                  bf16* __restrict__ xb_nxt, int s) {
  __shared__ union {
    struct { bf16 A[128 * 32]; bf16 Bv[128 * 32]; } st;
    float Cs[128 * 128];
  } sm;
  const int tid = threadIdx.x;
  const int m0 = blockIdx.x * 128;
  const int j0 = blockIdx.y * 32;
  const int r0 = tid >> 2, k0 = (tid & 3) * 8;
  const int nw0 = (r0 >> 5) * 512 + j0 + (r0 & 31);
  const int nw1 = (((r0 + 64) >> 5)) * 512 + j0 + ((r0 + 64) & 31);
  const bf16* aRow0 = xb_cur + (size_t)(m0 + r0) * 1024 + k0;
  const bf16* aRow1 = xb_cur + (size_t)(m0 + r0 + 64) * 1024 + k0;
  const bf16* bRow0 = Wcat + (size_t)nw0 * 1024 + k0;
  const bf16* bRow1 = Wcat + (size_t)nw1 * 1024 + k0;
  v4f acc[4][4];
  zero_acc(acc);
  gemm_mainloop<1024, false>(aRow0, aRow1, bRow0, bRow1, sm.st.A, sm.st.Bv, tid, acc);
  const int wave = tid >> 6, lane = tid & 63;
  const int wr = (wave >> 1) * 64, wc = (wave & 1) * 64;
  const int fr = lane & 15, fq = lane >> 4;
#pragma unroll
  for (int j = 0; j < 4; ++j) {
    int cl = wc + j * 16 + fr;
    int nw = (cl >> 5) * 512 + j0 + (cl & 31);
    float bias = b_ih[nw] + b_hh[nw];
    const float* ohcol = W_ih + (size_t)nw * 609 + 512;
#pragma unroll
    for (int i = 0; i < 4; ++i) {
#pragma unroll
      for (int r = 0; r < 4; ++r) {
        int rl = wr + i * 16 + fq * 4 + r;
        int tc = text[(size_t)(m0 + rl) * S_ + s];
        sm.Cs[rl * 128 + cl] = acc[i][j][r] + bias + ohcol[tc];
      }
    }
  }
  __syncthreads();
#pragma unroll
  for (int it = 0; it < 16; ++it) {
    int idx = tid + it * 256;
    int r = idx >> 5, q = idx & 31;
    float ig = sm.Cs[r * 128 + q];
    float fg = sm.Cs[r * 128 + 32 + q];
    float gg = sm.Cs[r * 128 + 64 + q];
    float og = sm.Cs[r * 128 + 96 + q];
    size_t cix = (size_t)(m0 + r) * 512 + j0 + q;
    float c2 = fast_sigmoid(fg) * c_state[cix] + fast_sigmoid(ig) * fast_tanh(gg);
    float h2 = fast_sigmoid(og) * fast_tanh(c2);
    c_state[cix] = c2;
    bf16 hb = (bf16)h2;
    xb_nxt[(size_t)(m0 + r) * 1024 + 512 + j0 + q] = hb;
    out_h[((size_t)(m0 + r) * S_ + s) * 512 + j0 + q] = hb;
  }
}

// probs = out_h . W_gen^T + b_gen
__global__ __launch_bounds__(256, 2) void k_gen(const bf16* __restrict__ out_h,
                                                const bf16* __restrict__ Wgen16,
                                                const float* __restrict__ b_gen,
                                                float* __restrict__ out) {
  __shared__ bf16 As[128 * 32];
  __shared__ bf16 Bs[128 * 32];
  const int tid = threadIdx.x;
  const int m0 = blockIdx.x * 128;
  const int r0 = tid >> 2, k0 = (tid & 3) * 8;
  const bf16* aRow0 = out_h + (size_t)(m0 + r0) * 512 + k0;
  const bf16* aRow1 = out_h + (size_t)(m0 + r0 + 64) * 512 + k0;
  const bf16* bRow0 = Wgen16 + (size_t)r0 * 512 + k0;
  const bf16* bRow1 = Wgen16 + (size_t)(r0 + 64) * 512 + k0;
  v4f acc[4][4];
  zero_acc(acc);
  gemm_mainloop<512, false>(aRow0, aRow1, bRow0, bRow1, As, Bs, tid, acc);
  const int wave = tid >> 6, lane = tid & 63;
  const int wr = (wave >> 1) * 64, wc = (wave & 1) * 64;
  const int fr = lane & 15, fq = lane >> 4;
#pragma unroll
  for (int i = 0; i < 4; ++i) {
#pragma unroll
    for (int j = 0; j < 4; ++j) {
      int col = wc + j * 16 + fr;
      if (col < C_) {
        float bg = b_gen[col];
#pragma unroll
        for (int r = 0; r < 4; ++r) {
          int row = m0 + wr + i * 16 + fq * 4 + r;
          out[(size_t)row * C_ + col] = acc[i][j][r] + bg;
        }
      }
    }
  }
}

// ---------------------------------------------------------------- launch
extern "C" void kernel_launch(void* const* d_in, const int* in_sizes, int n_in,
                              void* d_out, int out_size, void* d_ws, size_t ws_size,
                              hipStream_t stream) {
  (void)in_sizes; (void)n_in; (void)out_size;
  const float* batch_H = (const float*)d_in[0];
  const int*   text    = (const int*)d_in[1];
  const float* W_feat  = (const float*)d_in[2];
  const float* W_hid   = (const float*)d_in[3];
  const float* b_hid   = (const float*)d_in[4];
  const float* w_score = (const float*)d_in[5];
  const float* W_ih    = (const float*)d_in[6];
  const float* W_hh    = (const float*)d_in[7];
  const float* b_ih    = (const float*)d_in[8];
  const float* b_hh    = (const float*)d_in[9];
  const float* W_gen   = (const float*)d_in[10];
  const float* b_gen   = (const float*)d_in[11];
  float* out = (float*)d_out;

  char* ws = (char*)d_ws;
  bf16*  F       = (bf16*)(ws);                  // 67108864
  bf16*  out_h   = (bf16*)(ws + 67108864);       // 13631488
  float* P       = (float*)(ws + 80740352);      // 1048576
  bf16*  xb0     = (bf16*)(ws + 81788928);       // 1048576
  bf16*  xb1     = (bf16*)(ws + 82837504);       // 1048576
  float* c_state = (float*)(ws + 83886080);      // 1048576
  bf16*  Wcat    = (bf16*)(ws + 84934656);       // 4194304
  bf16*  Wf16    = (bf16*)(ws + 89128960);       // 524288
  bf16*  Whid16  = (bf16*)(ws + 89653248);       // 524288
  bf16*  Wgen16  = (bf16*)(ws + 90177536);       // 131072
  bf16*  bH16    = (bf16*)(ws + 90308608);       // 67108864 -> total 157417472
  const bool useBH16 = (ws_size >= (size_t)157417472);

  bf16* xb[2] = {xb0, xb1};

  hipMemsetAsync(xb0, 0, (size_t)512 * 1024 * 2, stream);
  hipMemsetAsync(c_state, 0, (size_t)512 * 512 * 4, stream);

  k_cvt<<<dim3(256), 256, 0, stream>>>(W_feat, Wf16, 512 * 512);
  k_cvt<<<dim3(256), 256, 0, stream>>>(W_hid, Whid16, 512 * 512);
  k_repack<<<dim3(2048), 256, 0, stream>>>(W_ih, W_hh, Wcat);
  k_prep_gen<<<dim3(128), 256, 0, stream>>>(W_gen, Wgen16);

  if (useBH16) {
    k_cvt<<<dim3(32768), 256, 0, stream>>>(batch_H, bH16, B_ * T_ * I_);
    k_feat<false><<<dim3(512, 4), 256, 0, stream>>>(bH16, Wf16, F);
  } else {
    k_feat<true><<<dim3(512, 4), 256, 0, stream>>>(batch_H, Wf16, F);
  }

  for (int s = 0; s < S_; ++s) {
    bf16* cur = xb[s & 1];
    bf16* nxt = xb[(s + 1) & 1];
    k_hp<<<dim3(8, 8), 256, 0, stream>>>(cur, Whid16, b_hid, P);
    if (useBH16) {
      k_attn<true><<<dim3(512), 256, 0, stream>>>(F, P, w_score, bH16, cur);
    } else {
      k_attn<false><<<dim3(512), 256, 0, stream>>>(F, P, w_score, batch_H, cur);
    }
    k_gates<<<dim3(4, 16), 256, 0, stream>>>(cur, Wcat, W_ih, b_ih, b_hh, text,
                                             c_state, out_h, nxt, s);
  }
  k_gen<<<dim3(104, 1), 256, 0, stream>>>(out_h, Wgen16, b_gen, out);
}

// Round 5
// 1863.247 us; speedup vs baseline: 1.3122x; 1.1640x over previous
//
#include <hip/hip_runtime.h>
#include <hip/hip_bf16.h>
#include <stdint.h>
#include <stddef.h>

typedef __bf16 bf16;
typedef __bf16 v8bf __attribute__((ext_vector_type(8)));
typedef float  v4f  __attribute__((ext_vector_type(4)));

#define B_ 512
#define T_ 128
#define I_ 512
#define H_ 512
#define C_ 97
#define S_ 26

// ---------------------------------------------------------------- helpers
__device__ __forceinline__ void async_copy16(void* lds, const void* g) {
  // global -> LDS direct copy, 16B/lane. Dest is wave-uniform base + lane*16
  // (we always pass base + tid*16B within each wave).
  __builtin_amdgcn_global_load_lds((__attribute__((address_space(1))) void*)g,
                                   (__attribute__((address_space(3))) void*)lds,
                                   16, 0, 0);
}

__device__ __forceinline__ float fast_tanh(float x) {
  float ax = __builtin_fabsf(x);
  float t  = __expf(-2.0f * ax);
  float r  = (1.0f - t) * __builtin_amdgcn_rcpf(1.0f + t);
  return __builtin_copysignf(r, x);
}
__device__ __forceinline__ float fast_sigmoid(float x) {
  float t = __expf(-x);
  return __builtin_amdgcn_rcpf(1.0f + t);
}

__device__ __forceinline__ void zero_acc(v4f acc[4][4]) {
  v4f z = {0.f, 0.f, 0.f, 0.f};
#pragma unroll
  for (int i = 0; i < 4; ++i)
#pragma unroll
    for (int j = 0; j < 4; ++j) acc[i][j] = z;
}

// ---------------------- 128x128xK mainloop, async global_load_lds staging
template <int KTOT>
__device__ __forceinline__ void mm_async(const bf16* aRow0, const bf16* aRow1,
                                         const bf16* bRow0, const bf16* bRow1,
                                         bf16* As, bf16* Bs, int tid,
                                         v4f acc[4][4]) {
  const int wave = tid >> 6, lane = tid & 63;
  const int wr = (wave >> 1) * 64, wc = (wave & 1) * 64;
  const int fr = lane & 15, fq = lane >> 4;
  bf16* a_d0 = As + tid * 8;          // == (tid>>2)*32 + (tid&3)*8  (tid*16B)
  bf16* a_d1 = As + (tid + 256) * 8;
  bf16* b_d0 = Bs + tid * 8;
  bf16* b_d1 = Bs + (tid + 256) * 8;
  const bf16* aF[4];
  const bf16* bF[4];
#pragma unroll
  for (int i = 0; i < 4; ++i) {
    aF[i] = As + (wr + i * 16 + fr) * 32 + fq * 8;
    bF[i] = Bs + (wc + i * 16 + fr) * 32 + fq * 8;
  }
  for (int kk = 0; kk < KTOT; kk += 32) {
    __syncthreads();  // previous iteration's readers done
    async_copy16(a_d0, aRow0 + kk);
    async_copy16(a_d1, aRow1 + kk);
    async_copy16(b_d0, bRow0 + kk);
    async_copy16(b_d1, bRow1 + kk);
    __syncthreads();  // drains vmcnt -> staging visible
    v8bf av[4], bv[4];
#pragma unroll
    for (int i = 0; i < 4; ++i) av[i] = *(const v8bf*)aF[i];
#pragma unroll
    for (int j = 0; j < 4; ++j) bv[j] = *(const v8bf*)bF[j];
#pragma unroll
    for (int i = 0; i < 4; ++i) {
#pragma unroll
      for (int j = 0; j < 4; ++j) {
        acc[i][j] = __builtin_amdgcn_mfma_f32_16x16x32_bf16(av[i], bv[j], acc[i][j], 0, 0, 0);
      }
    }
  }
  __syncthreads();
}

// ---------------------- fallback 128x128 mainloop (fp32 A, register staging)
template <int KTOT>
__device__ __forceinline__ void mm_reg_f32a(const float* aR0, const float* aR1,
                                            const bf16* bRow0, const bf16* bRow1,
                                            bf16* As, bf16* Bs, int tid,
                                            v4f acc[4][4]) {
  const int wave = tid >> 6, lane = tid & 63;
  const int wr = (wave >> 1) * 64, wc = (wave & 1) * 64;
  const int fr = lane & 15, fq = lane >> 4;
  bf16* a_s0 = As + tid * 8;
  bf16* a_s1 = As + (tid + 256) * 8;
  bf16* b_s0 = Bs + tid * 8;
  bf16* b_s1 = Bs + (tid + 256) * 8;
  const bf16* aF[4];
  const bf16* bF[4];
#pragma unroll
  for (int i = 0; i < 4; ++i) {
    aF[i] = As + (wr + i * 16 + fr) * 32 + fq * 8;
    bF[i] = Bs + (wc + i * 16 + fr) * 32 + fq * 8;
  }
  for (int kk = 0; kk < KTOT; kk += 32) {
    v8bf va0, va1;
    const float* p0 = aR0 + kk;
    const float* p1 = aR1 + kk;
    v4f f00 = ((const v4f*)p0)[0], f01 = ((const v4f*)p0)[1];
    v4f f10 = ((const v4f*)p1)[0], f11 = ((const v4f*)p1)[1];
#pragma unroll
    for (int j = 0; j < 4; ++j) {
      va0[j] = (bf16)f00[j]; va0[j + 4] = (bf16)f01[j];
      va1[j] = (bf16)f10[j]; va1[j + 4] = (bf16)f11[j];
    }
    v8bf vb0 = *(const v8bf*)(bRow0 + kk);
    v8bf vb1 = *(const v8bf*)(bRow1 + kk);
    __syncthreads();
    *(v8bf*)a_s0 = va0;
    *(v8bf*)a_s1 = va1;
    *(v8bf*)b_s0 = vb0;
    *(v8bf*)b_s1 = vb1;
    __syncthreads();
    v8bf av[4], bv[4];
#pragma unroll
    for (int i = 0; i < 4; ++i) av[i] = *(const v8bf*)aF[i];
#pragma unroll
    for (int j = 0; j < 4; ++j) bv[j] = *(const v8bf*)bF[j];
#pragma unroll
    for (int i = 0; i < 4; ++i) {
#pragma unroll
      for (int j = 0; j < 4; ++j) {
        acc[i][j] = __builtin_amdgcn_mfma_f32_16x16x32_bf16(av[i], bv[j], acc[i][j], 0, 0, 0);
      }
    }
  }
  __syncthreads();
}

// ---------------------------------------------------------------- prep
__global__ void k_cvt(const float* __restrict__ src, bf16* __restrict__ dst, int n) {
  int i = (blockIdx.x * 256 + threadIdx.x) * 4;
  if (i + 3 < n) {
    v4f f = *(const v4f*)(src + i);
#pragma unroll
    for (int j = 0; j < 4; ++j) dst[i + j] = (bf16)f[j];
  }
}

__global__ void k_repack(const float* __restrict__ Wih, const float* __restrict__ Whh,
                         bf16* __restrict__ Wcat) {
  int n = blockIdx.x;
  int t = threadIdx.x;
#pragma unroll
  for (int j = 0; j < 4; ++j) {
    int k = t * 4 + j;
    float v = (k < 512) ? Wih[(size_t)n * 609 + k] : Whh[(size_t)n * 512 + (k - 512)];
    Wcat[(size_t)n * 1024 + k] = (bf16)v;
  }
}

__global__ void k_prep_gen(const float* __restrict__ Wg, bf16* __restrict__ Wgen16) {
  int row = blockIdx.x;
  int t = threadIdx.x;
#pragma unroll
  for (int j = 0; j < 2; ++j) {
    int k = t * 2 + j;
    float v = (row < C_) ? Wg[(size_t)row * 512 + k] : 0.0f;
    Wgen16[(size_t)row * 512 + k] = (bf16)v;
  }
}

// OHT[c][n] = W_ih[n][512 + c]  (contiguous rows for the gates epilogue)
__global__ void k_prep_oht(const float* __restrict__ Wih, float* __restrict__ OHT) {
  int n = blockIdx.x * 256 + threadIdx.x;  // 0..2047
  const float* src = Wih + (size_t)n * 609 + 512;
  for (int c = 0; c < C_; ++c) OHT[(size_t)c * 2048 + n] = src[c];
}

// ---------------------------------------------------------------- kernels

// F = batch_H . W_feat^T (raw).  AF32: fallback path (fp32 A, register staging)
template <bool AF32>
__global__ __launch_bounds__(256, 2) void k_feat(const void* __restrict__ A,
                                                 const bf16* __restrict__ Bw,
                                                 bf16* __restrict__ F) {
  __shared__ bf16 As[128 * 32];
  __shared__ bf16 Bs[128 * 32];
  const int tid = threadIdx.x;
  const int m0 = blockIdx.x * 128, n0 = blockIdx.y * 128;
  const int r0 = tid >> 2, k0 = (tid & 3) * 8;
  const bf16* bRow0 = Bw + (size_t)(n0 + r0) * 512 + k0;
  const bf16* bRow1 = Bw + (size_t)(n0 + r0 + 64) * 512 + k0;
  v4f acc[4][4];
  zero_acc(acc);
  if (AF32) {
    const float* aRow0 = (const float*)A + (size_t)(m0 + r0) * 512 + k0;
    const float* aRow1 = (const float*)A + (size_t)(m0 + r0 + 64) * 512 + k0;
    mm_reg_f32a<512>(aRow0, aRow1, bRow0, bRow1, As, Bs, tid, acc);
  } else {
    const bf16* aRow0 = (const bf16*)A + (size_t)(m0 + r0) * 512 + k0;
    const bf16* aRow1 = (const bf16*)A + (size_t)(m0 + r0 + 64) * 512 + k0;
    mm_async<512>(aRow0, aRow1, bRow0, bRow1, As, Bs, tid, acc);
  }
  const int wave = tid >> 6, lane = tid & 63;
  const int wr = (wave >> 1) * 64, wc = (wave & 1) * 64;
  const int fr = lane & 15, fq = lane >> 4;
#pragma unroll
  for (int i = 0; i < 4; ++i) {
#pragma unroll
    for (int j = 0; j < 4; ++j) {
      int col = n0 + wc + j * 16 + fr;
#pragma unroll
      for (int r = 0; r < 4; ++r) {
        int row = m0 + wr + i * 16 + fq * 4 + r;
        F[(size_t)row * 512 + col] = (bf16)acc[i][j][r];
      }
    }
  }
}

// P = h . W_hid^T + b_hid (raw).  64x64 tiles, grid 8x8, async staging.
__global__ __launch_bounds__(256) void k_hp(const bf16* __restrict__ xb_cur,
                                            const bf16* __restrict__ Whid16,
                                            const float* __restrict__ b_hid,
                                            float* __restrict__ P) {
  __shared__ bf16 As[64 * 32];
  __shared__ bf16 Bs[64 * 32];
  const int tid = threadIdx.x, wave = tid >> 6, lane = tid & 63;
  const int m0 = blockIdx.x * 64, n0 = blockIdx.y * 64;
  const int r0 = tid >> 2, k0 = (tid & 3) * 8;
  const bf16* aRow = xb_cur + (size_t)(m0 + r0) * 1024 + 512 + k0;
  const bf16* bRow = Whid16 + (size_t)(n0 + r0) * 512 + k0;
  bf16* a_d = As + tid * 8;
  bf16* b_d = Bs + tid * 8;
  const int fr = lane & 15, fq = lane >> 4;
  const bf16* aF[4];
#pragma unroll
  for (int i = 0; i < 4; ++i) aF[i] = As + (i * 16 + fr) * 32 + fq * 8;
  const bf16* bF = Bs + (wave * 16 + fr) * 32 + fq * 8;
  v4f acc[4];
  v4f z = {0.f, 0.f, 0.f, 0.f};
#pragma unroll
  for (int i = 0; i < 4; ++i) acc[i] = z;
  for (int kk = 0; kk < 512; kk += 32) {
    __syncthreads();
    async_copy16(a_d, aRow + kk);
    async_copy16(b_d, bRow + kk);
    __syncthreads();
    v8bf bv = *(const v8bf*)bF;
#pragma unroll
    for (int i = 0; i < 4; ++i) {
      acc[i] = __builtin_amdgcn_mfma_f32_16x16x32_bf16(*(const v8bf*)aF[i], bv, acc[i], 0, 0, 0);
    }
  }
  const int col = n0 + wave * 16 + fr;
  const float bh = b_hid[col];
#pragma unroll
  for (int i = 0; i < 4; ++i) {
#pragma unroll
    for (int r = 0; r < 4; ++r) {
      int row = m0 + i * 16 + fq * 4 + r;
      P[(size_t)row * 512 + col] = acc[i][r] + bh;
    }
  }
}

// attention. CTX16: batch_H stream is bf16 (bH16) or fp32 (fallback).
template <bool CTX16>
__global__ __launch_bounds__(256) void k_attn(const bf16* __restrict__ F,
                                              const float* __restrict__ P,
                                              const float* __restrict__ w_score,
                                              const void* __restrict__ bHv,
                                              bf16* __restrict__ xb_cur) {
  const int b = blockIdx.x;
  const int tid = threadIdx.x, wave = tid >> 6, lane = tid & 63;
  __shared__ float e_s[T_];
  __shared__ float alpha_s[T_];
  __shared__ float red[4][I_];
  float Pv[8], Wv[8];
  {
    const float* p = P + (size_t)b * H_ + lane * 8;
#pragma unroll
    for (int j = 0; j < 8; ++j) Pv[j] = p[j];
    const float* w = w_score + lane * 8;
#pragma unroll
    for (int j = 0; j < 8; ++j) Wv[j] = w[j];
  }
  const bf16* Fb = F + (size_t)b * T_ * H_ + lane * 8;
  for (int t = wave; t < T_; t += 8) {
    v8bf Fv0 = *(const v8bf*)(Fb + (size_t)t * H_);
    v8bf Fv1 = *(const v8bf*)(Fb + (size_t)(t + 4) * H_);
    float a0 = 0.f, a1 = 0.f;
#pragma unroll
    for (int j = 0; j < 8; ++j) a0 = fmaf(Wv[j], fast_tanh((float)Fv0[j] + Pv[j]), a0);
#pragma unroll
    for (int j = 0; j < 8; ++j) a1 = fmaf(Wv[j], fast_tanh((float)Fv1[j] + Pv[j]), a1);
#pragma unroll
    for (int off = 32; off; off >>= 1) {
      a0 += __shfl_down(a0, off, 64);
      a1 += __shfl_down(a1, off, 64);
    }
    if (lane == 0) { e_s[t] = a0; e_s[t + 4] = a1; }
  }
  __syncthreads();
  if (wave == 0) {
    float e0 = e_s[lane], e1 = e_s[lane + 64];
    float m = fmaxf(e0, e1);
#pragma unroll
    for (int off = 32; off; off >>= 1) m = fmaxf(m, __shfl_down(m, off, 64));
    m = __shfl(m, 0, 64);
    float x0 = __expf(e0 - m), x1 = __expf(e1 - m);
    float ssum = x0 + x1;
#pragma unroll
    for (int off = 32; off; off >>= 1) ssum += __shfl_down(ssum, off, 64);
    ssum = __shfl(ssum, 0, 64);
    float inv = __builtin_amdgcn_rcpf(ssum);
    alpha_s[lane] = x0 * inv;
    alpha_s[lane + 64] = x1 * inv;
  }
  __syncthreads();
  const int i0 = lane * 8;
  float c[8];
#pragma unroll
  for (int j = 0; j < 8; ++j) c[j] = 0.f;
  if (CTX16) {
    const bf16* hb = (const bf16*)bHv + (size_t)b * T_ * I_ + i0;
    for (int t = wave; t < T_; t += 8) {
      float aa0 = alpha_s[t], aa1 = alpha_s[t + 4];
      v8bf p0 = *(const v8bf*)(hb + (size_t)t * I_);
      v8bf p1 = *(const v8bf*)(hb + (size_t)(t + 4) * I_);
#pragma unroll
      for (int j = 0; j < 8; ++j) c[j] = fmaf(aa0, (float)p0[j], c[j]);
#pragma unroll
      for (int j = 0; j < 8; ++j) c[j] = fmaf(aa1, (float)p1[j], c[j]);
    }
  } else {
    const float* hf = (const float*)bHv + (size_t)b * T_ * I_ + i0;
    for (int t = wave; t < T_; t += 8) {
      float aa0 = alpha_s[t], aa1 = alpha_s[t + 4];
      const float* p0 = hf + (size_t)t * I_;
      const float* p1 = hf + (size_t)(t + 4) * I_;
      v4f q00 = ((const v4f*)p0)[0], q01 = ((const v4f*)p0)[1];
      v4f q10 = ((const v4f*)p1)[0], q11 = ((const v4f*)p1)[1];
#pragma unroll
      for (int j = 0; j < 4; ++j) {
        c[j]     = fmaf(aa0, q00[j], c[j]);
        c[j + 4] = fmaf(aa0, q01[j], c[j + 4]);
        c[j]     = fmaf(aa1, q10[j], c[j]);
        c[j + 4] = fmaf(aa1, q11[j], c[j + 4]);
      }
    }
  }
#pragma unroll
  for (int j = 0; j < 8; ++j) red[wave][i0 + j] = c[j];
  __syncthreads();
#pragma unroll
  for (int v = 0; v < 2; ++v) {
    int i = tid * 2 + v;
    float s = red[0][i] + red[1][i] + red[2][i] + red[3][i];
    xb_cur[(size_t)b * 1024 + i] = (bf16)s;
  }
}

// gates GEMM (M=512, N=2048 permuted, K=1024) + fused one-hot/bias + LSTM
__global__ __launch_bounds__(256, 2) void k_gates(const bf16* __restrict__ xb_cur,
                                                  const bf16* __restrict__ Wcat,
                                                  const float* __restrict__ OHT,
                                                  const float* __restrict__ b_ih,
                                                  const float* __restrict__ b_hh,
                                                  const int* __restrict__ text,
                                                  float* __restrict__ c_state,
                                                  bf16* __restrict__ out_h,
                                                  bf16* __restrict__ xb_nxt, int s) {
  __shared__ union {
    struct { bf16 A[128 * 32]; bf16 Bv[128 * 32]; } st;
    float Cs[128 * 132];   // stride 132: 2-way (free) banking in epilogue
  } sm;
  const int tid = threadIdx.x;
  const int m0 = blockIdx.x * 128;
  const int j0 = blockIdx.y * 32;
  const int r0 = tid >> 2, k0 = (tid & 3) * 8;
  const int nw0 = (r0 >> 5) * 512 + j0 + (r0 & 31);
  const int nw1 = (((r0 + 64) >> 5)) * 512 + j0 + ((r0 + 64) & 31);
  const bf16* aRow0 = xb_cur + (size_t)(m0 + r0) * 1024 + k0;
  const bf16* aRow1 = xb_cur + (size_t)(m0 + r0 + 64) * 1024 + k0;
  const bf16* bRow0 = Wcat + (size_t)nw0 * 1024 + k0;
  const bf16* bRow1 = Wcat + (size_t)nw1 * 1024 + k0;
  v4f acc[4][4];
  zero_acc(acc);
  mm_async<1024>(aRow0, aRow1, bRow0, bRow1, sm.st.A, sm.st.Bv, tid, acc);
  const int wave = tid >> 6, lane = tid & 63;
  const int wr = (wave >> 1) * 64, wc = (wave & 1) * 64;
  const int fr = lane & 15, fq = lane >> 4;
  int tcv[4][4];
#pragma unroll
  for (int i = 0; i < 4; ++i) {
#pragma unroll
    for (int r = 0; r < 4; ++r) {
      tcv[i][r] = text[(size_t)(m0 + wr + i * 16 + fq * 4 + r) * S_ + s];
    }
  }
#pragma unroll
  for (int j = 0; j < 4; ++j) {
    int cl = wc + j * 16 + fr;
    int nw = (cl >> 5) * 512 + j0 + (cl & 31);
    float bias = b_ih[nw] + b_hh[nw];
    const float* oh = OHT + nw;
#pragma unroll
    for (int i = 0; i < 4; ++i) {
#pragma unroll
      for (int r = 0; r < 4; ++r) {
        int rl = wr + i * 16 + fq * 4 + r;
        sm.Cs[rl * 132 + cl] = acc[i][j][r] + bias + oh[(size_t)tcv[i][r] * 2048];
      }
    }
  }
  __syncthreads();
#pragma unroll
  for (int it = 0; it < 16; ++it) {
    int idx = tid + it * 256;
    int r = idx >> 5, q = idx & 31;
    float ig = sm.Cs[r * 132 + q];
    float fg = sm.Cs[r * 132 + 32 + q];
    float gg = sm.Cs[r * 132 + 64 + q];
    float og = sm.Cs[r * 132 + 96 + q];
    size_t cix = (size_t)(m0 + r) * 512 + j0 + q;
    float c2 = fast_sigmoid(fg) * c_state[cix] + fast_sigmoid(ig) * fast_tanh(gg);
    float h2 = fast_sigmoid(og) * fast_tanh(c2);
    c_state[cix] = c2;
    bf16 hb = (bf16)h2;
    xb_nxt[(size_t)(m0 + r) * 1024 + 512 + j0 + q] = hb;
    out_h[((size_t)(m0 + r) * S_ + s) * 512 + j0 + q] = hb;
  }
}

// probs = out_h . W_gen^T + b_gen
__global__ __launch_bounds__(256, 2) void k_gen(const bf16* __restrict__ out_h,
                                                const bf16* __restrict__ Wgen16,
                                                const float* __restrict__ b_gen,
                                                float* __restrict__ out) {
  __shared__ bf16 As[128 * 32];
  __shared__ bf16 Bs[128 * 32];
  const int tid = threadIdx.x;
  const int m0 = blockIdx.x * 128;
  const int r0 = tid >> 2, k0 = (tid & 3) * 8;
  const bf16* aRow0 = out_h + (size_t)(m0 + r0) * 512 + k0;
  const bf16* aRow1 = out_h + (size_t)(m0 + r0 + 64) * 512 + k0;
  const bf16* bRow0 = Wgen16 + (size_t)r0 * 512 + k0;
  const bf16* bRow1 = Wgen16 + (size_t)(r0 + 64) * 512 + k0;
  v4f acc[4][4];
  zero_acc(acc);
  mm_async<512>(aRow0, aRow1, bRow0, bRow1, As, Bs, tid, acc);
  const int wave = tid >> 6, lane = tid & 63;
  const int wr = (wave >> 1) * 64, wc = (wave & 1) * 64;
  const int fr = lane & 15, fq = lane >> 4;
#pragma unroll
  for (int i = 0; i < 4; ++i) {
#pragma unroll
    for (int j = 0; j < 4; ++j) {
      int col = wc + j * 16 + fr;
      if (col < C_) {
        float bg = b_gen[col];
#pragma unroll
        for (int r = 0; r < 4; ++r) {
          int row = m0 + wr + i * 16 + fq * 4 + r;
          out[(size_t)row * C_ + col] = acc[i][j][r] + bg;
        }
      }
    }
  }
}

// ---------------------------------------------------------------- launch
extern "C" void kernel_launch(void* const* d_in, const int* in_sizes, int n_in,
                              void* d_out, int out_size, void* d_ws, size_t ws_size,
                              hipStream_t stream) {
  (void)in_sizes; (void)n_in; (void)out_size;
  const float* batch_H = (const float*)d_in[0];
  const int*   text    = (const int*)d_in[1];
  const float* W_feat  = (const float*)d_in[2];
  const float* W_hid   = (const float*)d_in[3];
  const float* b_hid   = (const float*)d_in[4];
  const float* w_score = (const float*)d_in[5];
  const float* W_ih    = (const float*)d_in[6];
  const float* W_hh    = (const float*)d_in[7];
  const float* b_ih    = (const float*)d_in[8];
  const float* b_hh    = (const float*)d_in[9];
  const float* W_gen   = (const float*)d_in[10];
  const float* b_gen   = (const float*)d_in[11];
  float* out = (float*)d_out;

  char* ws = (char*)d_ws;
  bf16*  F       = (bf16*)(ws);                  // 67108864
  bf16*  out_h   = (bf16*)(ws + 67108864);       // 13631488
  float* P       = (float*)(ws + 80740352);      // 1048576
  bf16*  xb0     = (bf16*)(ws + 81788928);       // 1048576
  bf16*  xb1     = (bf16*)(ws + 82837504);       // 1048576
  float* c_state = (float*)(ws + 83886080);      // 1048576
  bf16*  Wcat    = (bf16*)(ws + 84934656);       // 4194304
  bf16*  Wf16    = (bf16*)(ws + 89128960);       // 524288
  bf16*  Whid16  = (bf16*)(ws + 89653248);       // 524288
  bf16*  Wgen16  = (bf16*)(ws + 90177536);       // 131072
  float* OHT     = (float*)(ws + 90308608);      // 794624 (pad to 1048576)
  bf16*  bH16    = (bf16*)(ws + 91357184);       // 67108864 -> total 158466048
  const bool useBH16 = (ws_size >= (size_t)158466048);

  bf16* xb[2] = {xb0, xb1};

  hipMemsetAsync(xb0, 0, (size_t)512 * 1024 * 2, stream);
  hipMemsetAsync(c_state, 0, (size_t)512 * 512 * 4, stream);

  k_cvt<<<dim3(256), 256, 0, stream>>>(W_feat, Wf16, 512 * 512);
  k_cvt<<<dim3(256), 256, 0, stream>>>(W_hid, Whid16, 512 * 512);
  k_repack<<<dim3(2048), 256, 0, stream>>>(W_ih, W_hh, Wcat);
  k_prep_gen<<<dim3(128), 256, 0, stream>>>(W_gen, Wgen16);
  k_prep_oht<<<dim3(8), 256, 0, stream>>>(W_ih, OHT);

  if (useBH16) {
    k_cvt<<<dim3(32768), 256, 0, stream>>>(batch_H, bH16, B_ * T_ * I_);
    k_feat<false><<<dim3(512, 4), 256, 0, stream>>>(bH16, Wf16, F);
  } else {
    k_feat<true><<<dim3(512, 4), 256, 0, stream>>>(batch_H, Wf16, F);
  }

  for (int s = 0; s < S_; ++s) {
    bf16* cur = xb[s & 1];
    bf16* nxt = xb[(s + 1) & 1];
    k_hp<<<dim3(8, 8), 256, 0, stream>>>(cur, Whid16, b_hid, P);
    if (useBH16) {
      k_attn<true><<<dim3(512), 256, 0, stream>>>(F, P, w_score, bH16, cur);
    } else {
      k_attn<false><<<dim3(512), 256, 0, stream>>>(F, P, w_score, batch_H, cur);
    }
    k_gates<<<dim3(4, 16), 256, 0, stream>>>(cur, Wcat, OHT, b_ih, b_hh, text,
                                             c_state, out_h, nxt, s);
  }
  k_gen<<<dim3(104, 1), 256, 0, stream>>>(out_h, Wgen16, b_gen, out);
}